// Round 1
// baseline (7926.552 us; speedup 1.0000x reference)
//
#include <hip/hip_runtime.h>

// Problem constants (match reference file)
#define NN      200000   // nodes
#define EA      600000   // attribute edges
#define ER      800000   // relational edges
#define NDIM    128      // node dim
#define EDIM    64       // edge dim
#define MDIM    128      // msg dim / out dim
#define NRELS   8

// ---------------- workspace layout (bytes) ----------------
// attr_sum  : NN*128 f32   @ 0            (102,400,000)
// cnt_attr  : NN    f32    @ OFF_CNTA
// cnt_rel   : NN*8  f32    @ OFF_CNTR
// unit_list : NN    i32    @ OFF_UL
// attr_list : NN    i32    @ OFF_AL
// rel_list  : 8*ER  i32    @ OFF_RL
// counters  : 10    i32    @ OFF_CT   [0]=unit cnt,[1]=attr cnt,[2..9]=rel cnt
static const size_t OFF_CNTA = (size_t)NN * 128 * 4;
static const size_t OFF_CNTR = OFF_CNTA + (size_t)NN * 4;
static const size_t OFF_UL   = OFF_CNTR + (size_t)NN * 8 * 4;
static const size_t OFF_AL   = OFF_UL + (size_t)NN * 4;
static const size_t OFF_RL   = OFF_AL + (size_t)NN * 4;
static const size_t OFF_CT   = OFF_RL + (size_t)NRELS * ER * 4;

// ---------------- GEMM micro-kernel ----------------
// 32 rows x 128 cols per block, 256 threads, 4x4 register tile per thread.
// cg = tid&31 -> 4 output cols (cg*4..+3); eg = tid>>5 -> 4 rows (eg*4..+3).
// Ws: [BK][128] row-major in LDS. X rows in LDS, stride xstride.
template <int BK>
__device__ __forceinline__ void mm_tile(const float* __restrict__ xbase, int xstride,
                                        const float* __restrict__ Ws, int cg,
                                        float acc[4][4]) {
#pragma unroll 4
  for (int kk = 0; kk < BK; kk += 4) {
    float4 wv[4];
#pragma unroll
    for (int q = 0; q < 4; ++q)
      wv[q] = *(const float4*)&Ws[(kk + q) * 128 + cg * 4];
#pragma unroll
    for (int i = 0; i < 4; ++i) {
      float4 xv = *(const float4*)&xbase[i * xstride + kk];
      float xa[4] = {xv.x, xv.y, xv.z, xv.w};
#pragma unroll
      for (int q = 0; q < 4; ++q) {
        const float* wq = (const float*)&wv[q];
#pragma unroll
        for (int c = 0; c < 4; ++c)
          acc[i][c] = fmaf(xa[q], wq[c], acc[i][c]);
      }
    }
  }
}

// ---------------- counting + compaction ----------------
__global__ __launch_bounds__(256) void k_count(
    const int* __restrict__ ei,    // [2][EA]
    const int* __restrict__ rei,   // [2][ER]
    const int* __restrict__ rtype, // [ER]
    const int* __restrict__ is_unit, // [NN]
    float* __restrict__ cnt_attr, float* __restrict__ cnt_rel,
    int* __restrict__ unit_list, int* __restrict__ attr_list,
    int* __restrict__ rel_list, int* __restrict__ counters) {
  int i = blockIdx.x * 256 + threadIdx.x;
  if (i < EA) atomicAdd(&cnt_attr[ei[EA + i]], 1.0f);
  if (i < ER) {
    int r = rtype[i];
    atomicAdd(&cnt_rel[rei[ER + i] * NRELS + r], 1.0f);
    int pos = atomicAdd(&counters[2 + r], 1);
    rel_list[r * ER + pos] = i;
  }
  if (i < NN) {
    int u = is_unit[i] != 0;
    int pos = atomicAdd(&counters[u ? 0 : 1], 1);
    (u ? unit_list : attr_list)[pos] = i;
  }
}

// ---------------- attribute edge messages ----------------
// m = relu([node_emb[src], edge_emb[e]] @ W_msg + b_msg) / cnt_attr[dst]
// atomically accumulated into attr_sum[dst].
__global__ __launch_bounds__(256) void k_attr_msg(
    const float* __restrict__ node_emb, const float* __restrict__ edge_emb,
    const float* __restrict__ W_msg, const float* __restrict__ b_msg,
    const int* __restrict__ ei, const float* __restrict__ cnt_attr,
    float* __restrict__ attr_sum) {
  __shared__ float Xs[32 * 192];
  __shared__ float Ws[64 * 128];
  const int tid = threadIdx.x;
  const int e0 = blockIdx.x * 32;
  const int* __restrict__ srcs = ei;
  const int* __restrict__ dsts = ei + EA;
  // stage X: 32 edges x 48 float4 (128 node + 64 edge feats)
  for (int idx = tid; idx < 32 * 48; idx += 256) {
    int e = idx / 48, p = idx % 48;
    int ge = e0 + e;  // EA % 32 == 0: no tail
    float4 v;
    if (p < 32) {
      int s = srcs[ge];
      v = ((const float4*)node_emb)[s * 32 + p];
    } else {
      v = ((const float4*)edge_emb)[(size_t)ge * 16 + (p - 32)];
    }
    *(float4*)&Xs[e * 192 + p * 4] = v;
  }
  float acc[4][4] = {};
  const int cg = tid & 31, eg = tid >> 5;
  for (int ch = 0; ch < 3; ++ch) {  // K = 192 = 3*64
    __syncthreads();
    for (int idx = tid; idx < 64 * 32; idx += 256)
      ((float4*)Ws)[idx] = ((const float4*)W_msg)[ch * 64 * 32 + idx];
    __syncthreads();
    mm_tile<64>(&Xs[(eg * 4) * 192 + ch * 64], 192, Ws, cg, acc);
  }
  const int j0 = cg * 4;
  float b[4] = {b_msg[j0], b_msg[j0 + 1], b_msg[j0 + 2], b_msg[j0 + 3]};
#pragma unroll
  for (int i = 0; i < 4; ++i) {
    int ge = e0 + eg * 4 + i;
    int d = dsts[ge];
    float inv = 1.0f / fmaxf(cnt_attr[d], 1.0f);
#pragma unroll
    for (int c = 0; c < 4; ++c) {
      float m = fmaxf(acc[i][c] + b[c], 0.0f) * inv;
      atomicAdd(&attr_sum[(size_t)d * 128 + j0 + c], m);
    }
  }
}

// ---------------- relational edge messages (bucketed by type) ----------------
__global__ __launch_bounds__(256) void k_rel_msg(
    const float* __restrict__ node_emb, const float* __restrict__ W_rel,
    const float* __restrict__ b_rel, const int* __restrict__ rei,
    const int* __restrict__ rel_list, const int* __restrict__ counters,
    const float* __restrict__ cnt_rel, float* __restrict__ rel_sum) {
  __shared__ float Xs[32 * 128];
  __shared__ float Ws[64 * 128];
  const int r = blockIdx.y;
  const int cnt = counters[2 + r];
  const int e0 = blockIdx.x * 32;
  if (e0 >= cnt) return;
  const int tid = threadIdx.x;
  const int* __restrict__ list = rel_list + (size_t)r * ER;
  const int* __restrict__ srcs = rei;
  const int* __restrict__ dsts = rei + ER;
  for (int idx = tid; idx < 32 * 32; idx += 256) {
    int e = idx >> 5, p = idx & 31;
    float4 v = make_float4(0.f, 0.f, 0.f, 0.f);
    if (e0 + e < cnt) {
      int ed = list[e0 + e];
      int s = srcs[ed];
      v = ((const float4*)node_emb)[s * 32 + p];
    }
    *(float4*)&Xs[e * 128 + p * 4] = v;
  }
  float acc[4][4] = {};
  const int cg = tid & 31, eg = tid >> 5;
  const float* __restrict__ Wg = W_rel + (size_t)r * 128 * 128;
  for (int ch = 0; ch < 2; ++ch) {  // K = 128 = 2*64
    __syncthreads();
    for (int idx = tid; idx < 64 * 32; idx += 256)
      ((float4*)Ws)[idx] = ((const float4*)Wg)[ch * 64 * 32 + idx];
    __syncthreads();
    mm_tile<64>(&Xs[(eg * 4) * 128 + ch * 64], 128, Ws, cg, acc);
  }
  const int j0 = cg * 4;
  float b[4] = {b_rel[r * 128 + j0], b_rel[r * 128 + j0 + 1],
                b_rel[r * 128 + j0 + 2], b_rel[r * 128 + j0 + 3]};
#pragma unroll
  for (int i = 0; i < 4; ++i) {
    int le = e0 + eg * 4 + i;
    if (le < cnt) {
      int ed = list[le];
      int d = dsts[ed];
      float inv = 1.0f / fmaxf(cnt_rel[d * NRELS + r], 1.0f);
#pragma unroll
      for (int c = 0; c < 4; ++c) {
        float m = fmaxf(acc[i][c] + b[c], 0.0f) * inv;
        atomicAdd(&rel_sum[(size_t)d * 128 + j0 + c], m);
      }
    }
  }
}

// ---------------- final node update over a compacted node list ----------------
// KT=384: [x | attr | rel] @ W_unit ; KT=256: [x | attr] @ W_attr
template <int KT>
__global__ __launch_bounds__(256) void k_final(
    const float* __restrict__ node_emb, const float* __restrict__ attr_sum,
    const float* __restrict__ relbuf, const float* __restrict__ Wg,
    const float* __restrict__ bg, const int* __restrict__ list,
    const int* __restrict__ cnt_ptr, float* __restrict__ out) {
  __shared__ float Xs[32 * KT];
  __shared__ float Ws[32 * 128];
  const int cnt = *cnt_ptr;
  const int n0 = blockIdx.x * 32;
  if (n0 >= cnt) return;
  const int tid = threadIdx.x;
  const int NP4 = KT / 4;  // float4 per node row: 96 or 64
  for (int idx = tid; idx < 32 * NP4; idx += 256) {
    int e = idx / NP4, p = idx % NP4;
    float4 v = make_float4(0.f, 0.f, 0.f, 0.f);
    if (n0 + e < cnt) {
      int vn = list[n0 + e];
      if (p < 32)       v = ((const float4*)node_emb)[(size_t)vn * 32 + p];
      else if (p < 64)  v = ((const float4*)attr_sum)[(size_t)vn * 32 + (p - 32)];
      else              v = ((const float4*)relbuf)[(size_t)vn * 32 + (p - 64)];
    }
    *(float4*)&Xs[e * KT + p * 4] = v;
  }
  float acc[4][4] = {};
  const int cg = tid & 31, eg = tid >> 5;
  for (int ch = 0; ch < KT / 32; ++ch) {
    __syncthreads();
    for (int idx = tid; idx < 32 * 32; idx += 256)
      ((float4*)Ws)[idx] = ((const float4*)Wg)[ch * 32 * 32 + idx];
    __syncthreads();
    mm_tile<32>(&Xs[(eg * 4) * KT + ch * 32], KT, Ws, cg, acc);
  }
  const int j0 = cg * 4;
  float b[4] = {bg[j0], bg[j0 + 1], bg[j0 + 2], bg[j0 + 3]};
#pragma unroll
  for (int i = 0; i < 4; ++i) {
    int ln = n0 + eg * 4 + i;
    if (ln < cnt) {
      int vn = list[ln];
      float4 h;
      h.x = fmaxf(acc[i][0] + b[0], 0.f);
      h.y = fmaxf(acc[i][1] + b[1], 0.f);
      h.z = fmaxf(acc[i][2] + b[2], 0.f);
      h.w = fmaxf(acc[i][3] + b[3], 0.f);
      ((float4*)out)[(size_t)vn * 32 + cg] = h;
    }
  }
}

extern "C" void kernel_launch(void* const* d_in, const int* in_sizes, int n_in,
                              void* d_out, int out_size, void* d_ws, size_t ws_size,
                              hipStream_t stream) {
  const float* node_emb = (const float*)d_in[0];
  const float* edge_emb = (const float*)d_in[1];
  const float* W_msg    = (const float*)d_in[2];
  const float* b_msg    = (const float*)d_in[3];
  const float* W_rel    = (const float*)d_in[4];
  const float* b_rel    = (const float*)d_in[5];
  const float* W_unit   = (const float*)d_in[6];
  const float* b_unit   = (const float*)d_in[7];
  const float* W_attr   = (const float*)d_in[8];
  const float* b_attr   = (const float*)d_in[9];
  const int* data_ei    = (const int*)d_in[10];
  const int* rel_ei     = (const int*)d_in[11];
  const int* rel_type   = (const int*)d_in[12];
  const int* is_unit    = (const int*)d_in[13];
  float* out = (float*)d_out;

  char* ws = (char*)d_ws;
  float* attr_sum  = (float*)(ws);
  float* cnt_attr  = (float*)(ws + OFF_CNTA);
  float* cnt_rel   = (float*)(ws + OFF_CNTR);
  int*   unit_list = (int*)(ws + OFF_UL);
  int*   attr_list = (int*)(ws + OFF_AL);
  int*   rel_list  = (int*)(ws + OFF_RL);
  int*   counters  = (int*)(ws + OFF_CT);

  // zero accumulators / counters; d_out doubles as the rel accumulator
  hipMemsetAsync(attr_sum, 0, (size_t)NN * 128 * 4, stream);
  hipMemsetAsync(cnt_attr, 0, (size_t)NN * 4, stream);
  hipMemsetAsync(cnt_rel, 0, (size_t)NN * 8 * 4, stream);
  hipMemsetAsync(counters, 0, 10 * 4, stream);
  hipMemsetAsync(out, 0, (size_t)NN * 128 * 4, stream);

  k_count<<<(ER + 255) / 256, 256, 0, stream>>>(
      data_ei, rel_ei, rel_type, is_unit, cnt_attr, cnt_rel, unit_list,
      attr_list, rel_list, counters);

  k_attr_msg<<<EA / 32, 256, 0, stream>>>(node_emb, edge_emb, W_msg, b_msg,
                                          data_ei, cnt_attr, attr_sum);

  k_rel_msg<<<dim3(ER / 32, NRELS), 256, 0, stream>>>(
      node_emb, W_rel, b_rel, rel_ei, rel_list, counters, cnt_rel, out);

  k_final<384><<<(NN + 31) / 32, 256, 0, stream>>>(
      node_emb, attr_sum, out, W_unit, b_unit, unit_list, &counters[0], out);
  k_final<256><<<(NN + 31) / 32, 256, 0, stream>>>(
      node_emb, attr_sum, out, W_attr, b_attr, attr_list, &counters[1], out);
}

// Round 2
// 3400.146 us; speedup vs baseline: 2.3312x; 2.3312x over previous
//
#include <hip/hip_runtime.h>

// Problem constants (match reference file)
#define NN      200000   // nodes
#define EA      600000   // attribute edges
#define ER      800000   // relational edges
#define NDIM    128      // node dim
#define EDIM    64       // edge dim
#define MDIM    128      // msg dim / out dim
#define NRELS   8

// ---------------- workspace layout (bytes) ----------------
static const size_t OFF_CNTA = (size_t)NN * 128 * 4;
static const size_t OFF_CNTR = OFF_CNTA + (size_t)NN * 4;
static const size_t OFF_UL   = OFF_CNTR + (size_t)NN * 8 * 4;
static const size_t OFF_AL   = OFF_UL + (size_t)NN * 4;
static const size_t OFF_RL   = OFF_AL + (size_t)NN * 4;
static const size_t OFF_CT   = OFF_RL + (size_t)NRELS * ER * 4;

// ---------------- GEMM micro-kernel ----------------
// 32 rows x 128 cols per block, 256 threads, 4x4 register tile per thread.
template <int BK>
__device__ __forceinline__ void mm_tile(const float* __restrict__ xbase, int xstride,
                                        const float* __restrict__ Ws, int cg,
                                        float acc[4][4]) {
#pragma unroll 4
  for (int kk = 0; kk < BK; kk += 4) {
    float4 wv[4];
#pragma unroll
    for (int q = 0; q < 4; ++q)
      wv[q] = *(const float4*)&Ws[(kk + q) * 128 + cg * 4];
#pragma unroll
    for (int i = 0; i < 4; ++i) {
      float4 xv = *(const float4*)&xbase[i * xstride + kk];
      float xa[4] = {xv.x, xv.y, xv.z, xv.w};
#pragma unroll
      for (int q = 0; q < 4; ++q) {
        const float* wq = (const float*)&wv[q];
#pragma unroll
        for (int c = 0; c < 4; ++c)
          acc[i][c] = fmaf(xa[q], wq[c], acc[i][c]);
      }
    }
  }
}

// ---------------- counting + compaction (hierarchical, low-contention) ------
// 625 blocks x 256 threads x 5 iters == ER exactly.
// Local ranks via LDS atomics; ONE global atomic per (block,type) to reserve
// the block's base; then scatter. Replaces 1M contended global atomics with
// 6250.
#define CGRID 625
#define CITER 5
__global__ __launch_bounds__(256) void k_compact(
    const int* __restrict__ ei,      // [2][EA]
    const int* __restrict__ rei,     // [2][ER]
    const int* __restrict__ rtype,   // [ER]
    const int* __restrict__ is_unit, // [NN]
    float* __restrict__ cnt_attr, float* __restrict__ cnt_rel,
    int* __restrict__ unit_list, int* __restrict__ attr_list,
    int* __restrict__ rel_list, int* __restrict__ counters) {
  __shared__ int lcnt[NRELS + 2];   // [0..7]=rel type, [8]=unit, [9]=attr
  __shared__ int lbase[NRELS + 2];
  const int tid = threadIdx.x;
  if (tid < NRELS + 2) lcnt[tid] = 0;
  __syncthreads();
  const int i0 = blockIdx.x * 256 * CITER;
  int ltype[CITER], lrank[CITER], ntype[CITER], nrank[CITER];
#pragma unroll
  for (int it = 0; it < CITER; ++it) {
    int i = i0 + it * 256 + tid;
    int r = rtype[i];
    ltype[it] = r;
    lrank[it] = atomicAdd(&lcnt[r], 1);
    atomicAdd(&cnt_rel[rei[ER + i] * NRELS + r], 1.0f);
    if (i < EA) atomicAdd(&cnt_attr[ei[EA + i]], 1.0f);
    if (i < NN) {
      int nt = (is_unit[i] != 0) ? 8 : 9;
      ntype[it] = nt;
      nrank[it] = atomicAdd(&lcnt[nt], 1);
    } else {
      ntype[it] = -1; nrank[it] = 0;
    }
  }
  __syncthreads();
  if (tid < NRELS + 2) {
    // counters: [0]=unit,[1]=attr,[2..9]=rel r
    int gidx = (tid < NRELS) ? (2 + tid) : (tid - NRELS);
    lbase[tid] = atomicAdd(&counters[gidx], lcnt[tid]);
  }
  __syncthreads();
#pragma unroll
  for (int it = 0; it < CITER; ++it) {
    int i = i0 + it * 256 + tid;
    int r = ltype[it];
    rel_list[(size_t)r * ER + lbase[r] + lrank[it]] = i;
    int nt = ntype[it];
    if (nt >= 0)
      ((nt == 8) ? unit_list : attr_list)[lbase[nt] + nrank[it]] = i;
  }
}

// ---------------- attribute edge messages ----------------
__global__ __launch_bounds__(256) void k_attr_msg(
    const float* __restrict__ node_emb, const float* __restrict__ edge_emb,
    const float* __restrict__ W_msg, const float* __restrict__ b_msg,
    const int* __restrict__ ei, const float* __restrict__ cnt_attr,
    float* __restrict__ attr_sum) {
  __shared__ float Xs[32 * 192];
  __shared__ float Ws[64 * 128];
  const int tid = threadIdx.x;
  const int e0 = blockIdx.x * 32;
  const int* __restrict__ srcs = ei;
  const int* __restrict__ dsts = ei + EA;
  for (int idx = tid; idx < 32 * 48; idx += 256) {
    int e = idx / 48, p = idx % 48;
    int ge = e0 + e;
    float4 v;
    if (p < 32) {
      int s = srcs[ge];
      v = ((const float4*)node_emb)[s * 32 + p];
    } else {
      v = ((const float4*)edge_emb)[(size_t)ge * 16 + (p - 32)];
    }
    *(float4*)&Xs[e * 192 + p * 4] = v;
  }
  float acc[4][4] = {};
  const int cg = tid & 31, eg = tid >> 5;
  for (int ch = 0; ch < 3; ++ch) {
    __syncthreads();
    for (int idx = tid; idx < 64 * 32; idx += 256)
      ((float4*)Ws)[idx] = ((const float4*)W_msg)[ch * 64 * 32 + idx];
    __syncthreads();
    mm_tile<64>(&Xs[(eg * 4) * 192 + ch * 64], 192, Ws, cg, acc);
  }
  const int j0 = cg * 4;
  float b[4] = {b_msg[j0], b_msg[j0 + 1], b_msg[j0 + 2], b_msg[j0 + 3]};
#pragma unroll
  for (int i = 0; i < 4; ++i) {
    int ge = e0 + eg * 4 + i;
    int d = dsts[ge];
    float inv = 1.0f / fmaxf(cnt_attr[d], 1.0f);
#pragma unroll
    for (int c = 0; c < 4; ++c) {
      float m = fmaxf(acc[i][c] + b[c], 0.0f) * inv;
      atomicAdd(&attr_sum[(size_t)d * 128 + j0 + c], m);
    }
  }
}

// ---------------- relational edge messages (bucketed by type) ----------------
__global__ __launch_bounds__(256) void k_rel_msg(
    const float* __restrict__ node_emb, const float* __restrict__ W_rel,
    const float* __restrict__ b_rel, const int* __restrict__ rei,
    const int* __restrict__ rel_list, const int* __restrict__ counters,
    const float* __restrict__ cnt_rel, float* __restrict__ rel_sum) {
  __shared__ float Xs[32 * 128];
  __shared__ float Ws[64 * 128];
  const int r = blockIdx.y;
  const int cnt = counters[2 + r];
  const int e0 = blockIdx.x * 32;
  if (e0 >= cnt) return;
  const int tid = threadIdx.x;
  const int* __restrict__ list = rel_list + (size_t)r * ER;
  const int* __restrict__ srcs = rei;
  const int* __restrict__ dsts = rei + ER;
  for (int idx = tid; idx < 32 * 32; idx += 256) {
    int e = idx >> 5, p = idx & 31;
    float4 v = make_float4(0.f, 0.f, 0.f, 0.f);
    if (e0 + e < cnt) {
      int ed = list[e0 + e];
      int s = srcs[ed];
      v = ((const float4*)node_emb)[s * 32 + p];
    }
    *(float4*)&Xs[e * 128 + p * 4] = v;
  }
  float acc[4][4] = {};
  const int cg = tid & 31, eg = tid >> 5;
  const float* __restrict__ Wg = W_rel + (size_t)r * 128 * 128;
  for (int ch = 0; ch < 2; ++ch) {
    __syncthreads();
    for (int idx = tid; idx < 64 * 32; idx += 256)
      ((float4*)Ws)[idx] = ((const float4*)Wg)[ch * 64 * 32 + idx];
    __syncthreads();
    mm_tile<64>(&Xs[(eg * 4) * 128 + ch * 64], 128, Ws, cg, acc);
  }
  const int j0 = cg * 4;
  float b[4] = {b_rel[r * 128 + j0], b_rel[r * 128 + j0 + 1],
                b_rel[r * 128 + j0 + 2], b_rel[r * 128 + j0 + 3]};
#pragma unroll
  for (int i = 0; i < 4; ++i) {
    int le = e0 + eg * 4 + i;
    if (le < cnt) {
      int ed = list[le];
      int d = dsts[ed];
      float inv = 1.0f / fmaxf(cnt_rel[d * NRELS + r], 1.0f);
#pragma unroll
      for (int c = 0; c < 4; ++c) {
        float m = fmaxf(acc[i][c] + b[c], 0.0f) * inv;
        atomicAdd(&rel_sum[(size_t)d * 128 + j0 + c], m);
      }
    }
  }
}

// ---------------- final node update over a compacted node list ----------------
template <int KT>
__global__ __launch_bounds__(256) void k_final(
    const float* __restrict__ node_emb, const float* __restrict__ attr_sum,
    const float* __restrict__ relbuf, const float* __restrict__ Wg,
    const float* __restrict__ bg, const int* __restrict__ list,
    const int* __restrict__ cnt_ptr, float* __restrict__ out) {
  __shared__ float Xs[32 * KT];
  __shared__ float Ws[32 * 128];
  const int cnt = *cnt_ptr;
  const int n0 = blockIdx.x * 32;
  if (n0 >= cnt) return;
  const int tid = threadIdx.x;
  const int NP4 = KT / 4;
  for (int idx = tid; idx < 32 * NP4; idx += 256) {
    int e = idx / NP4, p = idx % NP4;
    float4 v = make_float4(0.f, 0.f, 0.f, 0.f);
    if (n0 + e < cnt) {
      int vn = list[n0 + e];
      if (p < 32)       v = ((const float4*)node_emb)[(size_t)vn * 32 + p];
      else if (p < 64)  v = ((const float4*)attr_sum)[(size_t)vn * 32 + (p - 32)];
      else              v = ((const float4*)relbuf)[(size_t)vn * 32 + (p - 64)];
    }
    *(float4*)&Xs[e * KT + p * 4] = v;
  }
  float acc[4][4] = {};
  const int cg = tid & 31, eg = tid >> 5;
  for (int ch = 0; ch < KT / 32; ++ch) {
    __syncthreads();
    for (int idx = tid; idx < 32 * 32; idx += 256)
      ((float4*)Ws)[idx] = ((const float4*)Wg)[ch * 32 * 32 + idx];
    __syncthreads();
    mm_tile<32>(&Xs[(eg * 4) * KT + ch * 32], KT, Ws, cg, acc);
  }
  const int j0 = cg * 4;
  float b[4] = {bg[j0], bg[j0 + 1], bg[j0 + 2], bg[j0 + 3]};
#pragma unroll
  for (int i = 0; i < 4; ++i) {
    int ln = n0 + eg * 4 + i;
    if (ln < cnt) {
      int vn = list[ln];
      float4 h;
      h.x = fmaxf(acc[i][0] + b[0], 0.f);
      h.y = fmaxf(acc[i][1] + b[1], 0.f);
      h.z = fmaxf(acc[i][2] + b[2], 0.f);
      h.w = fmaxf(acc[i][3] + b[3], 0.f);
      ((float4*)out)[(size_t)vn * 32 + cg] = h;
    }
  }
}

extern "C" void kernel_launch(void* const* d_in, const int* in_sizes, int n_in,
                              void* d_out, int out_size, void* d_ws, size_t ws_size,
                              hipStream_t stream) {
  const float* node_emb = (const float*)d_in[0];
  const float* edge_emb = (const float*)d_in[1];
  const float* W_msg    = (const float*)d_in[2];
  const float* b_msg    = (const float*)d_in[3];
  const float* W_rel    = (const float*)d_in[4];
  const float* b_rel    = (const float*)d_in[5];
  const float* W_unit   = (const float*)d_in[6];
  const float* b_unit   = (const float*)d_in[7];
  const float* W_attr   = (const float*)d_in[8];
  const float* b_attr   = (const float*)d_in[9];
  const int* data_ei    = (const int*)d_in[10];
  const int* rel_ei     = (const int*)d_in[11];
  const int* rel_type   = (const int*)d_in[12];
  const int* is_unit    = (const int*)d_in[13];
  float* out = (float*)d_out;

  char* ws = (char*)d_ws;
  float* attr_sum  = (float*)(ws);
  float* cnt_attr  = (float*)(ws + OFF_CNTA);
  float* cnt_rel   = (float*)(ws + OFF_CNTR);
  int*   unit_list = (int*)(ws + OFF_UL);
  int*   attr_list = (int*)(ws + OFF_AL);
  int*   rel_list  = (int*)(ws + OFF_RL);
  int*   counters  = (int*)(ws + OFF_CT);

  hipMemsetAsync(attr_sum, 0, (size_t)NN * 128 * 4, stream);
  hipMemsetAsync(cnt_attr, 0, (size_t)NN * 4, stream);
  hipMemsetAsync(cnt_rel, 0, (size_t)NN * 8 * 4, stream);
  hipMemsetAsync(counters, 0, 10 * 4, stream);
  hipMemsetAsync(out, 0, (size_t)NN * 128 * 4, stream);

  k_compact<<<CGRID, 256, 0, stream>>>(
      data_ei, rel_ei, rel_type, is_unit, cnt_attr, cnt_rel, unit_list,
      attr_list, rel_list, counters);

  k_attr_msg<<<EA / 32, 256, 0, stream>>>(node_emb, edge_emb, W_msg, b_msg,
                                          data_ei, cnt_attr, attr_sum);

  k_rel_msg<<<dim3(ER / 32, NRELS), 256, 0, stream>>>(
      node_emb, W_rel, b_rel, rel_ei, rel_list, counters, cnt_rel, out);

  k_final<384><<<(NN + 31) / 32, 256, 0, stream>>>(
      node_emb, attr_sum, out, W_unit, b_unit, unit_list, &counters[0], out);
  k_final<256><<<(NN + 31) / 32, 256, 0, stream>>>(
      node_emb, attr_sum, out, W_attr, b_attr, attr_list, &counters[1], out);
}

// Round 3
// 2563.527 us; speedup vs baseline: 3.0920x; 1.3264x over previous
//
#include <hip/hip_runtime.h>
#include <hip/hip_fp16.h>

// Problem constants (match reference file)
#define NN      200000   // nodes
#define EA      600000   // attribute edges
#define ER      800000   // relational edges
#define NRELS   8

// counters[] indices
#define CT_UNIT   0   // unit node count / cursor
#define CT_ATTR   1   // attr node count / cursor
#define CT_TCNT   2   // ..9   per-type edge totals
#define CT_GA     10  // attr CSR global allocator
#define CT_GR     11  // rel CSR global allocator
#define CT_CURT   12  // ..19  per-type bucket cursors
#define CT_TBASE  20  // ..27  padded bucket bases
#define CT_PADTOT 28  // padded total list length

static constexpr size_t al(size_t x) { return (x + 255) & ~(size_t)255; }

// ---------------- workspace layout (bytes) ----------------
static const size_t O_CA = 0;                                    // u32[NN]
static const size_t O_CR = al(O_CA + (size_t)NN * 4);            // u32[NN*8]
static const size_t O_UL = al(O_CR + (size_t)NN * NRELS * 4);    // i32[NN]
static const size_t O_AL = al(O_UL + (size_t)NN * 4);            // i32[NN]
static const size_t O_RL = al(O_AL + (size_t)NN * 4);            // i32[ER+256]
static const size_t O_CT = al(O_RL + (size_t)(ER + 256) * 4);    // i32[32]
static const size_t O_P  = al(O_CT + 128);                       // path region
// Path 1 (CSR, needs ~533 MB):
static const size_t O_BA  = O_P;                                 // u32[NN]
static const size_t O_CUA = al(O_BA + (size_t)NN * 4);
static const size_t O_BR  = al(O_CUA + (size_t)NN * 4);
static const size_t O_CUR = al(O_BR + (size_t)NN * 4);
static const size_t O_XA  = al(O_CUR + (size_t)NN * 4);          // u32[EA]
static const size_t O_XR  = al(O_XA + (size_t)EA * 4);           // u32[ER]
static const size_t O_AS  = al(O_XR + (size_t)ER * 4);           // f32[NN*128]
static const size_t O_MB  = al(O_AS + (size_t)NN * 128 * 4);     // f32[(ER+256)*128]
static const size_t NEED1 = O_MB + (size_t)(ER + 256) * 128 * 4;
// Path 2 (f16 pk-atomic fallback, ~115 MB):
static const size_t O_AH = O_P;                                  // f16[NN*128]
static const size_t O_RH = al(O_AH + (size_t)NN * 128 * 2);      // f16[NN*128]

#define CGRID 625
#define CITER 5

// ---------------- pk f16 atomic add (inline asm; header/builtin-gating-proof)
__device__ __forceinline__ void pk_atomic_f16(__half* p, float a, float b) {
  __half2 hv = __floats2half2_rn(a, b);
  asm volatile("global_atomic_pk_add_f16 %0, %1, off" :: "v"(p), "v"(hv) : "memory");
}

// ---------------- GEMM micro-kernel (32 rows x 128 cols, 256 thr, 4x4/thread)
template <int BK>
__device__ __forceinline__ void mm_tile(const float* __restrict__ xbase, int xstride,
                                        const float* __restrict__ Ws, int cg,
                                        float acc[4][4]) {
#pragma unroll 4
  for (int kk = 0; kk < BK; kk += 4) {
    float4 wv[4];
#pragma unroll
    for (int q = 0; q < 4; ++q)
      wv[q] = *(const float4*)&Ws[(kk + q) * 128 + cg * 4];
#pragma unroll
    for (int i = 0; i < 4; ++i) {
      float4 xv = *(const float4*)&xbase[i * xstride + kk];
      float xa[4] = {xv.x, xv.y, xv.z, xv.w};
#pragma unroll
      for (int q = 0; q < 4; ++q) {
        const float* wq = (const float*)&wv[q];
#pragma unroll
        for (int c = 0; c < 4; ++c)
          acc[i][c] = fmaf(xa[q], wq[c], acc[i][c]);
      }
    }
  }
}

// ---------------- pass 1: counts + type totals + node compaction -------------
__global__ __launch_bounds__(256) void k_count(
    const int* __restrict__ ei, const int* __restrict__ rei,
    const int* __restrict__ rtype, const int* __restrict__ is_unit,
    unsigned* __restrict__ cnt_attr, unsigned* __restrict__ cnt_rel,
    int* __restrict__ unit_list, int* __restrict__ attr_list,
    int* __restrict__ counters) {
  __shared__ int lcnt[NRELS + 2], lbase[NRELS + 2];
  const int tid = threadIdx.x;
  if (tid < NRELS + 2) lcnt[tid] = 0;
  __syncthreads();
  const int i0 = blockIdx.x * 256 * CITER;
  int ntype[CITER], nrank[CITER];
#pragma unroll
  for (int it = 0; it < CITER; ++it) {
    int i = i0 + it * 256 + tid;
    int r = rtype[i];
    atomicAdd(&lcnt[r], 1);
    atomicAdd(&cnt_rel[(size_t)rei[ER + i] * NRELS + r], 1u);
    if (i < EA) atomicAdd(&cnt_attr[ei[EA + i]], 1u);
    if (i < NN) {
      int nt = (is_unit[i] != 0) ? NRELS : NRELS + 1;
      ntype[it] = nt;
      nrank[it] = atomicAdd(&lcnt[nt], 1);
    } else { ntype[it] = -1; nrank[it] = 0; }
  }
  __syncthreads();
  if (tid < NRELS + 2) {
    int g = (tid < NRELS) ? (CT_TCNT + tid) : (tid - NRELS);
    lbase[tid] = atomicAdd(&counters[g], lcnt[tid]);
  }
  __syncthreads();
#pragma unroll
  for (int it = 0; it < CITER; ++it) {
    int i = i0 + it * 256 + tid;
    int nt = ntype[it];
    if (nt >= 0)
      ((nt == NRELS) ? unit_list : attr_list)[lbase[nt] + nrank[it]] = i;
  }
}

// ---------------- pass 2: padded type bases; per-dst CSR bases ---------------
template <bool CSR>
__global__ __launch_bounds__(256) void k_base(
    const unsigned* __restrict__ cnt_attr, const unsigned* __restrict__ cnt_rel,
    unsigned* __restrict__ base_a, unsigned* __restrict__ cur_a,
    unsigned* __restrict__ base_r, unsigned* __restrict__ cur_r,
    int* __restrict__ counters) {
  if (blockIdx.x == 0 && threadIdx.x == 0) {
    int tb = 0;
    for (int r = 0; r < NRELS; ++r) {
      counters[CT_TBASE + r] = tb;
      counters[CT_CURT + r] = tb;
      tb += (counters[CT_TCNT + r] + 31) & ~31;
    }
    counters[CT_PADTOT] = tb;
  }
  if constexpr (CSR) {
    __shared__ unsigned ls[2], gb[2];
    if (threadIdx.x < 2) ls[threadIdx.x] = 0;
    __syncthreads();
    int v = blockIdx.x * 256 + threadIdx.x;
    unsigned da = 0, dr = 0, la = 0, lr = 0;
    if (v < NN) {
      da = cnt_attr[v];
      const uint4* cr = (const uint4*)&cnt_rel[(size_t)v * NRELS];
      uint4 c0 = cr[0], c1 = cr[1];
      dr = c0.x + c0.y + c0.z + c0.w + c1.x + c1.y + c1.z + c1.w;
      la = atomicAdd(&ls[0], da);
      lr = atomicAdd(&ls[1], dr);
    }
    __syncthreads();
    if (threadIdx.x == 0) {
      gb[0] = atomicAdd((unsigned*)&counters[CT_GA], ls[0]);
      gb[1] = atomicAdd((unsigned*)&counters[CT_GR], ls[1]);
    }
    __syncthreads();
    if (v < NN) {
      base_a[v] = gb[0] + la; cur_a[v] = gb[0] + la;
      base_r[v] = gb[1] + lr; cur_r[v] = gb[1] + lr;
    }
  }
}

// ---------------- pass 3: bucketed rel list + CSR slot lists -----------------
template <bool CSR>
__global__ __launch_bounds__(256) void k_fill(
    const int* __restrict__ ei, const int* __restrict__ rei,
    const int* __restrict__ rtype, int* __restrict__ rlist,
    unsigned* __restrict__ cur_a, unsigned* __restrict__ cur_r,
    unsigned* __restrict__ csr_a, unsigned* __restrict__ csr_r,
    int* __restrict__ counters) {
  __shared__ int lcnt[NRELS], lbase[NRELS];
  const int tid = threadIdx.x;
  if (tid < NRELS) lcnt[tid] = 0;
  __syncthreads();
  const int i0 = blockIdx.x * 256 * CITER;
  int ltype[CITER], lrank[CITER];
#pragma unroll
  for (int it = 0; it < CITER; ++it) {
    int i = i0 + it * 256 + tid;
    int r = rtype[i];
    ltype[it] = r;
    lrank[it] = atomicAdd(&lcnt[r], 1);
    if constexpr (CSR) {
      if (i < EA) {
        unsigned ms = atomicAdd(&cur_a[ei[EA + i]], 1u);
        csr_a[ms] = (unsigned)i;
      }
    }
  }
  __syncthreads();
  if (tid < NRELS) lbase[tid] = atomicAdd(&counters[CT_CURT + tid], lcnt[tid]);
  __syncthreads();
#pragma unroll
  for (int it = 0; it < CITER; ++it) {
    int i = i0 + it * 256 + tid;
    int slot = lbase[ltype[it]] + lrank[it];
    rlist[slot] = i;
    if constexpr (CSR) {
      unsigned ms = atomicAdd(&cur_r[rei[ER + i]], 1u);
      csr_r[ms] = (unsigned)slot;
    }
  }
}

// ---------------- attribute edge messages ----------------
// PATH 1: plain store of m/cnt into msg[e]; PATH 2: pk f16 atomics.
template <int PATH>
__global__ __launch_bounds__(256) void k_attr_msg(
    const float* __restrict__ node_emb, const float* __restrict__ edge_emb,
    const float* __restrict__ W_msg, const float* __restrict__ b_msg,
    const int* __restrict__ ei, const unsigned* __restrict__ cnt_attr,
    float* __restrict__ msg, __half* __restrict__ attrh) {
  __shared__ float Xs[32 * 192];
  __shared__ float Ws[64 * 128];
  const int tid = threadIdx.x;
  const int e0 = blockIdx.x * 32;
  const int* __restrict__ srcs = ei;
  const int* __restrict__ dsts = ei + EA;
  for (int idx = tid; idx < 32 * 48; idx += 256) {
    int e = idx / 48, p = idx % 48;
    int ge = e0 + e;
    float4 v;
    if (p < 32) v = ((const float4*)node_emb)[(size_t)srcs[ge] * 32 + p];
    else        v = ((const float4*)edge_emb)[(size_t)ge * 16 + (p - 32)];
    *(float4*)&Xs[e * 192 + p * 4] = v;
  }
  float acc[4][4] = {};
  const int cg = tid & 31, eg = tid >> 5;
  for (int ch = 0; ch < 3; ++ch) {
    __syncthreads();
    for (int idx = tid; idx < 64 * 32; idx += 256)
      ((float4*)Ws)[idx] = ((const float4*)W_msg)[ch * 64 * 32 + idx];
    __syncthreads();
    mm_tile<64>(&Xs[(eg * 4) * 192 + ch * 64], 192, Ws, cg, acc);
  }
  const int j0 = cg * 4;
  float b[4] = {b_msg[j0], b_msg[j0 + 1], b_msg[j0 + 2], b_msg[j0 + 3]};
#pragma unroll
  for (int i = 0; i < 4; ++i) {
    int ge = e0 + eg * 4 + i;
    int d = dsts[ge];
    float inv = 1.0f / fmaxf((float)cnt_attr[d], 1.0f);
    float m0 = fmaxf(acc[i][0] + b[0], 0.f) * inv;
    float m1 = fmaxf(acc[i][1] + b[1], 0.f) * inv;
    float m2 = fmaxf(acc[i][2] + b[2], 0.f) * inv;
    float m3 = fmaxf(acc[i][3] + b[3], 0.f) * inv;
    if (PATH == 1) {
      *(float4*)&msg[(size_t)ge * 128 + j0] = make_float4(m0, m1, m2, m3);
    } else {
      pk_atomic_f16(&attrh[(size_t)d * 128 + j0], m0, m1);
      pk_atomic_f16(&attrh[(size_t)d * 128 + j0 + 2], m2, m3);
    }
  }
}

// ---------------- relational edge messages (padded concat buckets) -----------
template <int PATH>
__global__ __launch_bounds__(256) void k_rel_msg(
    const float* __restrict__ node_emb, const float* __restrict__ W_rel,
    const float* __restrict__ b_rel, const int* __restrict__ rei,
    const int* __restrict__ rlist, const unsigned* __restrict__ cnt_rel,
    const int* __restrict__ counters, float* __restrict__ msg,
    __half* __restrict__ relh) {
  __shared__ float Xs[32 * 128];
  __shared__ float Ws[64 * 128];
  __shared__ int eds[32];
  const int e0 = blockIdx.x * 32;
  if (e0 >= counters[CT_PADTOT]) return;
  int r = NRELS - 1;
#pragma unroll
  for (int j = NRELS - 1; j >= 1; --j)
    if (e0 < counters[CT_TBASE + j]) r = j - 1;
  const int tid = threadIdx.x;
  const int* __restrict__ srcs = rei;
  const int* __restrict__ dsts = rei + ER;
  for (int idx = tid; idx < 32 * 32; idx += 256) {
    int e = idx >> 5, p = idx & 31;
    int ed = rlist[e0 + e];
    if (p == 0) eds[e] = ed;
    float4 v = make_float4(0.f, 0.f, 0.f, 0.f);
    if (ed >= 0) v = ((const float4*)node_emb)[(size_t)srcs[ed] * 32 + p];
    *(float4*)&Xs[e * 128 + p * 4] = v;
  }
  float acc[4][4] = {};
  const int cg = tid & 31, eg = tid >> 5;
  const float* __restrict__ Wg = W_rel + (size_t)r * 128 * 128;
  for (int ch = 0; ch < 2; ++ch) {
    __syncthreads();
    for (int idx = tid; idx < 64 * 32; idx += 256)
      ((float4*)Ws)[idx] = ((const float4*)Wg)[ch * 64 * 32 + idx];
    __syncthreads();
    mm_tile<64>(&Xs[(eg * 4) * 128 + ch * 64], 128, Ws, cg, acc);
  }
  const int j0 = cg * 4;
  float b[4] = {b_rel[r * 128 + j0], b_rel[r * 128 + j0 + 1],
                b_rel[r * 128 + j0 + 2], b_rel[r * 128 + j0 + 3]};
#pragma unroll
  for (int i = 0; i < 4; ++i) {
    int le = e0 + eg * 4 + i;
    int ed = eds[eg * 4 + i];
    if (ed >= 0) {
      int d = dsts[ed];
      float inv = 1.0f / fmaxf((float)cnt_rel[(size_t)d * NRELS + r], 1.0f);
      float m0 = fmaxf(acc[i][0] + b[0], 0.f) * inv;
      float m1 = fmaxf(acc[i][1] + b[1], 0.f) * inv;
      float m2 = fmaxf(acc[i][2] + b[2], 0.f) * inv;
      float m3 = fmaxf(acc[i][3] + b[3], 0.f) * inv;
      if (PATH == 1) {
        *(float4*)&msg[(size_t)le * 128 + j0] = make_float4(m0, m1, m2, m3);
      } else {
        pk_atomic_f16(&relh[(size_t)d * 128 + j0], m0, m1);
        pk_atomic_f16(&relh[(size_t)d * 128 + j0 + 2], m2, m3);
      }
    }
  }
}

// ---------------- segmented reduce: out[v] = sum of msg rows in CSR range ----
__global__ __launch_bounds__(256) void k_reduce(
    const float* __restrict__ msg, const unsigned* __restrict__ csr,
    const unsigned* __restrict__ base, const unsigned* __restrict__ cur,
    float* __restrict__ out) {
  int v = blockIdx.x * 2 + (threadIdx.x >> 7);
  int l = threadIdx.x & 127;
  unsigned b = base[v], e = cur[v];
  float acc = 0.f;
  for (unsigned k = b; k < e; ++k)
    acc += msg[(size_t)csr[k] * 128 + l];
  out[(size_t)v * 128 + l] = acc;
}

// ---------------- final node update over a compacted node list ---------------
template <int KT, bool HALF>
__global__ __launch_bounds__(256) void k_final(
    const float* __restrict__ node_emb, const float* __restrict__ attr_f,
    const float* __restrict__ rel_f, const __half* __restrict__ attr_h,
    const __half* __restrict__ rel_h, const float* __restrict__ Wg,
    const float* __restrict__ bg, const int* __restrict__ list,
    const int* __restrict__ cnt_ptr, float* __restrict__ out) {
  __shared__ float Xs[32 * KT];
  __shared__ float Ws[32 * 128];
  const int cnt = *cnt_ptr;
  const int n0 = blockIdx.x * 32;
  if (n0 >= cnt) return;
  const int tid = threadIdx.x;
  const int NP4 = KT / 4;
  for (int idx = tid; idx < 32 * NP4; idx += 256) {
    int e = idx / NP4, p = idx % NP4;
    float4 v = make_float4(0.f, 0.f, 0.f, 0.f);
    if (n0 + e < cnt) {
      int vn = list[n0 + e];
      if (p < 32) {
        v = ((const float4*)node_emb)[(size_t)vn * 32 + p];
      } else if (!HALF) {
        v = (p < 64) ? ((const float4*)attr_f)[(size_t)vn * 32 + (p - 32)]
                     : ((const float4*)rel_f)[(size_t)vn * 32 + (p - 64)];
      } else {
        const __half* s = (p < 64) ? attr_h : rel_h;
        int q = (p < 64) ? (p - 32) : (p - 64);
        __half2 h0 = *(const __half2*)&s[(size_t)vn * 128 + q * 4];
        __half2 h1 = *(const __half2*)&s[(size_t)vn * 128 + q * 4 + 2];
        float2 f0 = __half22float2(h0), f1 = __half22float2(h1);
        v = make_float4(f0.x, f0.y, f1.x, f1.y);
      }
    }
    *(float4*)&Xs[e * KT + p * 4] = v;
  }
  float acc[4][4] = {};
  const int cg = tid & 31, eg = tid >> 5;
  for (int ch = 0; ch < KT / 32; ++ch) {
    __syncthreads();
    for (int idx = tid; idx < 32 * 32; idx += 256)
      ((float4*)Ws)[idx] = ((const float4*)Wg)[ch * 32 * 32 + idx];
    __syncthreads();
    mm_tile<32>(&Xs[(eg * 4) * KT + ch * 32], KT, Ws, cg, acc);
  }
  const int j0 = cg * 4;
  float b[4] = {bg[j0], bg[j0 + 1], bg[j0 + 2], bg[j0 + 3]};
#pragma unroll
  for (int i = 0; i < 4; ++i) {
    int ln = n0 + eg * 4 + i;
    if (ln < cnt) {
      int vn = list[ln];
      float4 h;
      h.x = fmaxf(acc[i][0] + b[0], 0.f);
      h.y = fmaxf(acc[i][1] + b[1], 0.f);
      h.z = fmaxf(acc[i][2] + b[2], 0.f);
      h.w = fmaxf(acc[i][3] + b[3], 0.f);
      ((float4*)out)[(size_t)vn * 32 + cg] = h;
    }
  }
}

extern "C" void kernel_launch(void* const* d_in, const int* in_sizes, int n_in,
                              void* d_out, int out_size, void* d_ws, size_t ws_size,
                              hipStream_t stream) {
  const float* node_emb = (const float*)d_in[0];
  const float* edge_emb = (const float*)d_in[1];
  const float* W_msg    = (const float*)d_in[2];
  const float* b_msg    = (const float*)d_in[3];
  const float* W_rel    = (const float*)d_in[4];
  const float* b_rel    = (const float*)d_in[5];
  const float* W_unit   = (const float*)d_in[6];
  const float* b_unit   = (const float*)d_in[7];
  const float* W_attr   = (const float*)d_in[8];
  const float* b_attr   = (const float*)d_in[9];
  const int* data_ei    = (const int*)d_in[10];
  const int* rel_ei     = (const int*)d_in[11];
  const int* rel_type   = (const int*)d_in[12];
  const int* is_unit    = (const int*)d_in[13];
  float* out = (float*)d_out;

  char* ws = (char*)d_ws;
  unsigned* cnt_attr = (unsigned*)(ws + O_CA);
  unsigned* cnt_rel  = (unsigned*)(ws + O_CR);
  int* unit_list = (int*)(ws + O_UL);
  int* attr_list = (int*)(ws + O_AL);
  int* rlist     = (int*)(ws + O_RL);
  int* counters  = (int*)(ws + O_CT);

  const bool full = ws_size >= NEED1;

  hipMemsetAsync(ws + O_CA, 0, (size_t)NN * 4, stream);
  hipMemsetAsync(ws + O_CR, 0, (size_t)NN * NRELS * 4, stream);
  hipMemsetAsync(ws + O_CT, 0, 128, stream);
  hipMemsetAsync(ws + O_RL, 0xFF, (size_t)(ER + 256) * 4, stream);

  k_count<<<CGRID, 256, 0, stream>>>(data_ei, rel_ei, rel_type, is_unit,
                                     cnt_attr, cnt_rel, unit_list, attr_list,
                                     counters);

  if (full) {  // ---- Path 1: CSR scatter + segmented reduce, no f32 atomics
    unsigned* base_a = (unsigned*)(ws + O_BA);
    unsigned* cur_a  = (unsigned*)(ws + O_CUA);
    unsigned* base_r = (unsigned*)(ws + O_BR);
    unsigned* cur_r  = (unsigned*)(ws + O_CUR);
    unsigned* csr_a  = (unsigned*)(ws + O_XA);
    unsigned* csr_r  = (unsigned*)(ws + O_XR);
    float* attr_sum  = (float*)(ws + O_AS);
    float* msg       = (float*)(ws + O_MB);

    k_base<true><<<(NN + 255) / 256, 256, 0, stream>>>(
        cnt_attr, cnt_rel, base_a, cur_a, base_r, cur_r, counters);
    k_fill<true><<<CGRID, 256, 0, stream>>>(
        data_ei, rel_ei, rel_type, rlist, cur_a, cur_r, csr_a, csr_r, counters);

    k_attr_msg<1><<<EA / 32, 256, 0, stream>>>(
        node_emb, edge_emb, W_msg, b_msg, data_ei, cnt_attr, msg, nullptr);
    k_reduce<<<NN / 2, 256, 0, stream>>>(msg, csr_a, base_a, cur_a, attr_sum);

    k_rel_msg<1><<<(ER + 8 * 31 + 31) / 32, 256, 0, stream>>>(
        node_emb, W_rel, b_rel, rel_ei, rlist, cnt_rel, counters, msg, nullptr);
    k_reduce<<<NN / 2, 256, 0, stream>>>(msg, csr_r, base_r, cur_r, out);

    k_final<384, false><<<(NN + 31) / 32, 256, 0, stream>>>(
        node_emb, attr_sum, out, nullptr, nullptr, W_unit, b_unit, unit_list,
        &counters[CT_UNIT], out);
    k_final<256, false><<<(NN + 31) / 32, 256, 0, stream>>>(
        node_emb, attr_sum, attr_sum, nullptr, nullptr, W_attr, b_attr,
        attr_list, &counters[CT_ATTR], out);
  } else {  // ---- Path 2: pk f16 atomic accumulators
    __half* attrh = (__half*)(ws + O_AH);
    __half* relh  = (__half*)(ws + O_RH);
    hipMemsetAsync(ws + O_AH, 0, (size_t)NN * 128 * 2 * 2, stream);

    k_base<false><<<1, 64, 0, stream>>>(cnt_attr, cnt_rel, nullptr, nullptr,
                                        nullptr, nullptr, counters);
    k_fill<false><<<CGRID, 256, 0, stream>>>(
        data_ei, rel_ei, rel_type, rlist, nullptr, nullptr, nullptr, nullptr,
        counters);

    k_attr_msg<2><<<EA / 32, 256, 0, stream>>>(
        node_emb, edge_emb, W_msg, b_msg, data_ei, cnt_attr, nullptr, attrh);
    k_rel_msg<2><<<(ER + 8 * 31 + 31) / 32, 256, 0, stream>>>(
        node_emb, W_rel, b_rel, rel_ei, rlist, cnt_rel, counters, nullptr, relh);

    k_final<384, true><<<(NN + 31) / 32, 256, 0, stream>>>(
        node_emb, nullptr, nullptr, attrh, relh, W_unit, b_unit, unit_list,
        &counters[CT_UNIT], out);
    k_final<256, true><<<(NN + 31) / 32, 256, 0, stream>>>(
        node_emb, nullptr, nullptr, attrh, attrh, W_attr, b_attr, attr_list,
        &counters[CT_ATTR], out);
  }
}